// Round 2
// baseline (615.914 us; speedup 1.0000x reference)
//
#include <hip/hip_runtime.h>

// GNN GRU cell, B=4096 L=50 E=128, split-bf16 MFMA, one block per graph.

using f32x4 = __attribute__((ext_vector_type(4))) float;
using s16x8 = __attribute__((ext_vector_type(8))) short;
using s16x4 = __attribute__((ext_vector_type(4))) short;

#define MFMA(a, b, c) __builtin_amdgcn_mfma_f32_16x16x32_bf16((a), (b), (c), 0, 0, 0)

__device__ __forceinline__ unsigned short f2bf(float x) {
    unsigned u = __float_as_uint(x);
    u += 0x7fffu + ((u >> 16) & 1u);
    return (unsigned short)(u >> 16);
}
__device__ __forceinline__ float bf2f(unsigned short b) {
    return __uint_as_float(((unsigned)b) << 16);
}

// ---- prologue: weights f32 -> bf16 into workspace --------------------------
// W1  [640][128]: rows 0-127 = w_in, 128-255 = w_out, 256-639 = w_hh
// Wih [384][256]
__global__ void wconv_kernel(const float* __restrict__ w_in, const float* __restrict__ w_out,
                             const float* __restrict__ w_hh, const float* __restrict__ w_ih,
                             unsigned short* __restrict__ W1, unsigned short* __restrict__ Wih) {
    int i = blockIdx.x * 256 + threadIdx.x;
    if (i < 81920) {
        float v = (i < 16384) ? w_in[i] : (i < 32768) ? w_out[i - 16384] : w_hh[i - 32768];
        W1[i] = f2bf(v);
    } else if (i < 180224) {
        int j = i - 81920;
        Wih[j] = f2bf(w_ih[j]);
    }
}

// LDS layout (bytes):
//   sHhi [64][136] @ 0        sHlo @ 17408        (hidden split planes, rows>=50 zero)
//   sAhi [64][136] @ 34816    sAlo @ 52224        (A: cols 0-63 = A_in (pad), 64-127 = A_out (pad))
//   overlay @ 69632:
//     phase A: sThi [256][72] @ 69632, sTlo @ 106496   (h_ioT transposed, split)
//     phase B: sIhi [64][264] @ 69632, sIlo @ 103424   (inputs row-major, split)
#define LDS_BYTES 143360

__launch_bounds__(512, 1)
__global__ void gnn_kernel(const float* __restrict__ A, const float* __restrict__ H,
                           const unsigned short* __restrict__ W1, const unsigned short* __restrict__ Wih,
                           const float* __restrict__ b_ih, const float* __restrict__ b_hh,
                           const float* __restrict__ b_iah, const float* __restrict__ b_ioh,
                           const float* __restrict__ b_in, const float* __restrict__ b_out,
                           float* __restrict__ out) {
    extern __shared__ char smem[];
    unsigned short* sHhi = (unsigned short*)(smem + 0);
    unsigned short* sHlo = (unsigned short*)(smem + 17408);
    unsigned short* sAhi = (unsigned short*)(smem + 34816);
    unsigned short* sAlo = (unsigned short*)(smem + 52224);
    unsigned short* sThi = (unsigned short*)(smem + 69632);
    unsigned short* sTlo = (unsigned short*)(smem + 106496);
    unsigned short* sIhi = (unsigned short*)(smem + 69632);
    unsigned short* sIlo = (unsigned short*)(smem + 103424);

    const int b    = blockIdx.x;
    const int tid  = threadIdx.x;
    const int wv   = tid >> 6;
    const int lane = tid & 63;
    const int l16  = lane & 15;
    const int l4   = lane >> 4;

    const float* Hb = H + (size_t)b * 6400;
    const float* Ab = A + (size_t)b * 5000;

    // ---- S0: stage hidden & A as split-bf16 planes (zero-padded) ----
    #pragma unroll
    for (int it = 0; it < 16; ++it) {
        int idx = it * 512 + tid;
        int r = idx >> 7, c = idx & 127;
        float x = (r < 50) ? Hb[r * 128 + c] : 0.f;
        unsigned short xh = f2bf(x);
        sHhi[r * 136 + c] = xh;
        sHlo[r * 136 + c] = f2bf(x - bf2f(xh));
        float a = 0.f;
        if (r < 50) {
            if (c < 64) { if (c < 50) a = Ab[r * 100 + c]; }
            else        { int k = c - 64; if (k < 50) a = Ab[r * 100 + 50 + k]; }
        }
        unsigned short ah16 = f2bf(a);
        sAhi[r * 136 + c] = ah16;
        sAlo[r * 136 + c] = f2bf(a - bf2f(ah16));
    }
    __syncthreads();

    const f32x4 vzero = {0.f, 0.f, 0.f, 0.f};

    // ---- P1: Y1[64][640] = hidden @ [w_in|w_out|w_hh]^T ----
    // wave wv owns n-tiles {wv, wv+8} (h_io) and {wv+16, wv+24, wv+32} (gh, kept in regs)
    f32x4 acc_io[2][4];
    f32x4 acc_gh[3][4];
    #pragma unroll
    for (int t = 0; t < 2; ++t)
        #pragma unroll
        for (int m = 0; m < 4; ++m) acc_io[t][m] = vzero;
    #pragma unroll
    for (int t = 0; t < 3; ++t)
        #pragma unroll
        for (int m = 0; m < 4; ++m) acc_gh[t][m] = vzero;

    #pragma unroll 1
    for (int kt = 0; kt < 4; ++kt) {
        s16x8 ah[4], al[4];
        #pragma unroll
        for (int mt = 0; mt < 4; ++mt) {
            int off = (mt * 16 + l16) * 136 + kt * 32 + l4 * 8;
            ah[mt] = *(const s16x8*)(sHhi + off);
            al[mt] = *(const s16x8*)(sHlo + off);
        }
        s16x8 bfr[5];
        #pragma unroll
        for (int t = 0; t < 5; ++t) {
            int row = (wv + 8 * t) * 16 + l16;
            bfr[t] = *(const s16x8*)(W1 + row * 128 + kt * 32 + l4 * 8);
        }
        #pragma unroll
        for (int t = 0; t < 5; ++t) {
            #pragma unroll
            for (int mt = 0; mt < 4; ++mt) {
                if (t < 2) {
                    f32x4 acc = acc_io[t][mt];
                    acc = MFMA(ah[mt], bfr[t], acc);
                    acc = MFMA(al[mt], bfr[t], acc);
                    acc_io[t][mt] = acc;
                } else {
                    f32x4 acc = acc_gh[t - 2][mt];
                    acc = MFMA(ah[mt], bfr[t], acc);
                    acc = MFMA(al[mt], bfr[t], acc);
                    acc_gh[t - 2][mt] = acc;
                }
            }
        }
    }
    // write h_ioT transposed, + b_in/b_out, split
    #pragma unroll
    for (int t = 0; t < 2; ++t) {
        int n = (wv + 8 * t) * 16 + l16;             // 0..255
        float bias = (n < 128) ? b_in[n] : b_out[n - 128];
        #pragma unroll
        for (int mt = 0; mt < 4; ++mt) {
            int mb = mt * 16 + l4 * 4;
            s16x4 vhi, vlo;
            #pragma unroll
            for (int r = 0; r < 4; ++r) {
                float x = acc_io[t][mt][r] + bias;
                unsigned short xh = f2bf(x);
                vhi[r] = (short)xh;
                vlo[r] = (short)f2bf(x - bf2f(xh));
            }
            *(s16x4*)(sThi + n * 72 + mb) = vhi;
            *(s16x4*)(sTlo + n * 72 + mb) = vlo;
        }
    }
    __syncthreads();

    // ---- P2: inputs[64][256] = [A_in @ h_in | A_out @ h_out] ----
    // wave: p = part (0=in,1=out), n-tiles {q, q+4} within part
    const int p = wv >> 2, q = wv & 3;
    f32x4 acc2[2][4];
    #pragma unroll
    for (int t = 0; t < 2; ++t)
        #pragma unroll
        for (int m = 0; m < 4; ++m) acc2[t][m] = vzero;

    #pragma unroll 1
    for (int kt = 0; kt < 2; ++kt) {
        s16x8 ah[4], al[4];
        #pragma unroll
        for (int mt = 0; mt < 4; ++mt) {
            int off = (mt * 16 + l16) * 136 + p * 64 + kt * 32 + l4 * 8;
            ah[mt] = *(const s16x8*)(sAhi + off);
            al[mt] = *(const s16x8*)(sAlo + off);
        }
        #pragma unroll
        for (int t = 0; t < 2; ++t) {
            int hr = p * 128 + (q + 4 * t) * 16 + l16;
            int boff = hr * 72 + kt * 32 + l4 * 8;
            s16x8 bh = *(const s16x8*)(sThi + boff);
            s16x8 bl = *(const s16x8*)(sTlo + boff);
            #pragma unroll
            for (int mt = 0; mt < 4; ++mt) {
                f32x4 acc = acc2[t][mt];
                acc = MFMA(ah[mt], bh, acc);   // A_hi * h_hi
                acc = MFMA(ah[mt], bl, acc);   // A_hi * h_lo
                acc = MFMA(al[mt], bh, acc);   // A_lo * h_hi
                acc2[t][mt] = acc;
            }
        }
    }
    __syncthreads();   // all waves done READING sT -> overlay may be overwritten
    #pragma unroll
    for (int t = 0; t < 2; ++t) {
        int n = p * 128 + (q + 4 * t) * 16 + l16;    // 0..255
        float bias = (n < 128) ? b_iah[n] : b_ioh[n - 128];
        #pragma unroll
        for (int mt = 0; mt < 4; ++mt) {
            int mb = mt * 16 + l4 * 4;
            #pragma unroll
            for (int r = 0; r < 4; ++r) {
                float x = acc2[t][mt][r] + bias;
                unsigned short xh = f2bf(x);
                sIhi[(mb + r) * 264 + n] = xh;
                sIlo[(mb + r) * 264 + n] = f2bf(x - bf2f(xh));
            }
        }
    }
    __syncthreads();

    // ---- P3: gi[64][384] = inputs @ w_ih^T, accumulated into gh accs ----
    // wave wv: gi n-tiles {wv, wv+8, wv+16}; t=0,1 add into acc_gh, t=2 separate (needs h_n apart)
    f32x4 acc_n[4];
    #pragma unroll
    for (int m = 0; m < 4; ++m) acc_n[m] = vzero;

    #pragma unroll 1
    for (int kt = 0; kt < 8; ++kt) {
        s16x8 ah[4], al[4];
        #pragma unroll
        for (int mt = 0; mt < 4; ++mt) {
            int off = (mt * 16 + l16) * 264 + kt * 32 + l4 * 8;
            ah[mt] = *(const s16x8*)(sIhi + off);
            al[mt] = *(const s16x8*)(sIlo + off);
        }
        s16x8 bfr[3];
        #pragma unroll
        for (int t = 0; t < 3; ++t) {
            int row = (wv + 8 * t) * 16 + l16;
            bfr[t] = *(const s16x8*)(Wih + row * 256 + kt * 32 + l4 * 8);
        }
        #pragma unroll
        for (int t = 0; t < 3; ++t) {
            #pragma unroll
            for (int mt = 0; mt < 4; ++mt) {
                if (t < 2) {
                    f32x4 acc = acc_gh[t][mt];
                    acc = MFMA(ah[mt], bfr[t], acc);
                    acc = MFMA(al[mt], bfr[t], acc);
                    acc_gh[t][mt] = acc;
                } else {
                    f32x4 acc = acc_n[mt];
                    acc = MFMA(ah[mt], bfr[t], acc);
                    acc = MFMA(al[mt], bfr[t], acc);
                    acc_n[mt] = acc;
                }
            }
        }
    }

    // ---- gates + store; wave wv handles e in [16*wv, 16*wv+16) ----
    {
        const int e = wv * 16 + l16;
        const float br   = b_ih[e]       + b_hh[e];
        const float bi   = b_ih[128 + e] + b_hh[128 + e];
        const float bn_i = b_ih[256 + e];
        const float bn_h = b_hh[256 + e];
        float* Ob = out + (size_t)b * 6400;
        #pragma unroll
        for (int mt = 0; mt < 4; ++mt) {
            #pragma unroll
            for (int r = 0; r < 4; ++r) {
                int m = mt * 16 + l4 * 4 + r;
                if (m < 50) {
                    float argr = acc_gh[0][mt][r] + br;
                    float argi = acc_gh[1][mt][r] + bi;
                    float i_n  = acc_n[mt][r] + bn_i;
                    float h_n  = acc_gh[2][mt][r] + bn_h;
                    float rg = 1.f / (1.f + __expf(-argr));
                    float ig = 1.f / (1.f + __expf(-argi));
                    float ta = i_n + rg * h_n;
                    ta = fminf(fmaxf(ta, -30.f), 30.f);
                    float ex = __expf(2.f * ta);
                    float ng = (ex - 1.f) / (ex + 1.f);
                    float h0 = bf2f(sHhi[m * 136 + e]) + bf2f(sHlo[m * 136 + e]);
                    Ob[m * 128 + e] = h0 + ig * (ng - h0);
                }
            }
        }
    }
}

extern "C" void kernel_launch(void* const* d_in, const int* in_sizes, int n_in,
                              void* d_out, int out_size, void* d_ws, size_t ws_size,
                              hipStream_t stream) {
    const float* A     = (const float*)d_in[0];
    const float* hidden= (const float*)d_in[1];
    const float* w_ih  = (const float*)d_in[2];
    const float* w_hh  = (const float*)d_in[3];
    const float* b_ih  = (const float*)d_in[4];
    const float* b_hh  = (const float*)d_in[5];
    const float* b_iah = (const float*)d_in[6];
    const float* b_ioh = (const float*)d_in[7];
    const float* w_in  = (const float*)d_in[8];
    const float* b_in  = (const float*)d_in[9];
    const float* w_out = (const float*)d_in[10];
    const float* b_out = (const float*)d_in[11];
    float* out = (float*)d_out;

    unsigned short* W1  = (unsigned short*)d_ws;      // 81920 bf16
    unsigned short* Wih = W1 + 81920;                 // 98304 bf16

    wconv_kernel<<<704, 256, 0, stream>>>(w_in, w_out, w_hh, w_ih, W1, Wih);

    const int nbatch = in_sizes[1] / 6400;            // 4096
    (void)hipFuncSetAttribute((const void*)gnn_kernel,
                              hipFuncAttributeMaxDynamicSharedMemorySize, LDS_BYTES);
    gnn_kernel<<<nbatch, 512, LDS_BYTES, stream>>>(A, hidden, W1, Wih,
                                                   b_ih, b_hh, b_iah, b_ioh,
                                                   b_in, b_out, out);
}

// Round 3
// 542.423 us; speedup vs baseline: 1.1355x; 1.1355x over previous
//
#include <hip/hip_runtime.h>

// GNN GRU cell, B=4096 L=50 E=128, split-bf16 MFMA, one block per graph.
// R3: reg-prefetched weights, double-buffered LDS frags, vectorized staging,
//     pk-cvt splits, A hi-plane only.

using f32x4 = __attribute__((ext_vector_type(4))) float;
using s16x8 = __attribute__((ext_vector_type(8))) short;
using u32x2 = __attribute__((ext_vector_type(2))) unsigned;

#define MFMA(a, b, c) __builtin_amdgcn_mfma_f32_16x16x32_bf16((a), (b), (c), 0, 0, 0)

__device__ __forceinline__ unsigned short f2bf(float x) {
    unsigned u = __float_as_uint(x);
    u += 0x7fffu + ((u >> 16) & 1u);
    return (unsigned short)(u >> 16);
}
__device__ __forceinline__ float bf2f(unsigned short b) {
    return __uint_as_float(((unsigned)b) << 16);
}
// packed f32x2 -> bf16x2 (dst.lo16 = cvt(a), dst.hi16 = cvt(b))
__device__ __forceinline__ unsigned pkbf(float a, float b) {
    unsigned r;
    asm("v_cvt_pk_bf16_f32 %0, %1, %2" : "=v"(r) : "v"(a), "v"(b));
    return r;
}

// ---- prologue: weights f32 -> bf16 into workspace --------------------------
// W1  [640][128]: rows 0-127 = w_in, 128-255 = w_out, 256-639 = w_hh
// Wih [384][256]
__global__ void wconv_kernel(const float* __restrict__ w_in, const float* __restrict__ w_out,
                             const float* __restrict__ w_hh, const float* __restrict__ w_ih,
                             unsigned short* __restrict__ W1, unsigned short* __restrict__ Wih) {
    int i = blockIdx.x * 256 + threadIdx.x;
    if (i < 81920) {
        float v = (i < 16384) ? w_in[i] : (i < 32768) ? w_out[i - 16384] : w_hh[i - 32768];
        W1[i] = f2bf(v);
    } else if (i < 180224) {
        int j = i - 81920;
        Wih[j] = f2bf(w_ih[j]);
    }
}

// LDS layout (bytes):
//   sHhi [64][136] @ 0        sHlo @ 17408      (hidden split planes, rows>=50 zero)
//   sAhi [64][136] @ 34816                      (A hi only: cols 0-63 in, 64-127 out)
//   overlay @ 52224:
//     phase A: sThi [256][72] @ 52224, sTlo @ 89088   (h_ioT transposed, split) end 125952
//     phase B: sIhi [64][264] @ 52224, sIlo @ 86016   (inputs row-major, split) end 119808
#define LDS_BYTES 125952

__launch_bounds__(512, 1)
__global__ void gnn_kernel(const float* __restrict__ A, const float* __restrict__ H,
                           const unsigned short* __restrict__ W1, const unsigned short* __restrict__ Wih,
                           const float* __restrict__ b_ih, const float* __restrict__ b_hh,
                           const float* __restrict__ b_iah, const float* __restrict__ b_ioh,
                           const float* __restrict__ b_in, const float* __restrict__ b_out,
                           float* __restrict__ out) {
    extern __shared__ char smem[];
    unsigned short* sHhi = (unsigned short*)(smem + 0);
    unsigned short* sHlo = (unsigned short*)(smem + 17408);
    unsigned short* sAhi = (unsigned short*)(smem + 34816);
    unsigned short* sThi = (unsigned short*)(smem + 52224);
    unsigned short* sTlo = (unsigned short*)(smem + 89088);
    unsigned short* sIhi = (unsigned short*)(smem + 52224);
    unsigned short* sIlo = (unsigned short*)(smem + 86016);

    const int b    = blockIdx.x;
    const int tid  = threadIdx.x;
    const int wv   = tid >> 6;
    const int lane = tid & 63;
    const int l16  = lane & 15;
    const int l4   = lane >> 4;

    const float* Hb = H + (size_t)b * 6400;
    const float* Ab = A + (size_t)b * 5000;

    // ---- W1 fragment prefetch (global->reg; latency hides under S0) ----
    s16x8 w1f[4][5];
    #pragma unroll
    for (int kt = 0; kt < 4; ++kt)
        #pragma unroll
        for (int t = 0; t < 5; ++t)
            w1f[kt][t] = *(const s16x8*)(W1 + ((wv + 8 * t) * 16 + l16) * 128 + kt * 32 + l4 * 8);

    // ---- S0: stage hidden (split) & A (hi only), vectorized ----
    {
        const float4* H4 = (const float4*)Hb;
        #pragma unroll
        for (int i = 0; i < 4; ++i) {
            int idx = i * 512 + tid;
            if (idx < 1600) {
                int r = idx >> 5, c = (idx & 31) * 4;
                float4 v = H4[idx];
                unsigned h01 = pkbf(v.x, v.y), h23 = pkbf(v.z, v.w);
                float g0 = __uint_as_float(h01 << 16), g1 = __uint_as_float(h01 & 0xffff0000u);
                float g2 = __uint_as_float(h23 << 16), g3 = __uint_as_float(h23 & 0xffff0000u);
                unsigned l01 = pkbf(v.x - g0, v.y - g1), l23 = pkbf(v.z - g2, v.w - g3);
                u32x2 vh; vh[0] = h01; vh[1] = h23;
                u32x2 vl; vl[0] = l01; vl[1] = l23;
                *(u32x2*)(sHhi + r * 136 + c) = vh;
                *(u32x2*)(sHlo + r * 136 + c) = vl;
            }
        }
        // zero H rows 50-63 (cols 0-127) in both planes
        #pragma unroll
        for (int i = 0; i < 4; ++i) {
            int idx = i * 512 + tid;
            if (idx < 1792) {
                int pl = idx >= 896 ? 1 : 0;
                int j = idx - pl * 896;
                int r = 50 + (j >> 6), c = (j & 63) * 2;
                *(unsigned*)((pl ? sHlo : sHhi) + r * 136 + c) = 0u;
            }
        }
        const float2* A2 = (const float2*)Ab;
        #pragma unroll
        for (int i = 0; i < 5; ++i) {
            int idx = i * 512 + tid;
            if (idx < 2500) {
                int r = idx / 50, j = idx - r * 50;
                float2 v = A2[idx];
                int dc = (j < 25) ? (2 * j) : (2 * j + 14);   // out half at 64+(2j-50)
                *(unsigned*)(sAhi + r * 136 + dc) = pkbf(v.x, v.y);
            }
        }
        // zero A pads: rows 0-49 cols 50-63 & 114-127; rows 50-63 cols 0-127
        #pragma unroll
        for (int i = 0; i < 4; ++i) {
            int idx = i * 512 + tid;
            if (idx < 1596) {
                int r, c;
                if (idx < 700) {
                    r = idx / 14; int k = idx - r * 14;
                    c = (k < 7) ? (50 + 2 * k) : (100 + 2 * k);
                } else {
                    int j = idx - 700;
                    r = 50 + (j >> 6); c = (j & 63) * 2;
                }
                *(unsigned*)(sAhi + r * 136 + c) = 0u;
            }
        }
    }
    __syncthreads();

    const f32x4 vzero = {0.f, 0.f, 0.f, 0.f};

    // ---- P1: Y1[64][640] = hidden @ [w_in|w_out|w_hh]^T ----
    f32x4 acc_io[2][4];
    f32x4 acc_gh[3][4];
    #pragma unroll
    for (int t = 0; t < 2; ++t)
        #pragma unroll
        for (int m = 0; m < 4; ++m) acc_io[t][m] = vzero;
    #pragma unroll
    for (int t = 0; t < 3; ++t)
        #pragma unroll
        for (int m = 0; m < 4; ++m) acc_gh[t][m] = vzero;

    s16x8 ah[2][4], al[2][4];
    #pragma unroll
    for (int mt = 0; mt < 4; ++mt) {
        int off = (mt * 16 + l16) * 136 + l4 * 8;
        ah[0][mt] = *(const s16x8*)(sHhi + off);
        al[0][mt] = *(const s16x8*)(sHlo + off);
    }
    #pragma unroll
    for (int kt = 0; kt < 4; ++kt) {
        const int cur = kt & 1, nxt = cur ^ 1;
        if (kt < 3) {
            #pragma unroll
            for (int mt = 0; mt < 4; ++mt) {
                int off = (mt * 16 + l16) * 136 + (kt + 1) * 32 + l4 * 8;
                ah[nxt][mt] = *(const s16x8*)(sHhi + off);
                al[nxt][mt] = *(const s16x8*)(sHlo + off);
            }
        }
        #pragma unroll
        for (int t = 0; t < 5; ++t)
            #pragma unroll
            for (int mt = 0; mt < 4; ++mt) {
                if (t < 2) {
                    f32x4 a = acc_io[t][mt];
                    a = MFMA(ah[cur][mt], w1f[kt][t], a);
                    a = MFMA(al[cur][mt], w1f[kt][t], a);
                    acc_io[t][mt] = a;
                } else {
                    f32x4 a = acc_gh[t - 2][mt];
                    a = MFMA(ah[cur][mt], w1f[kt][t], a);
                    a = MFMA(al[cur][mt], w1f[kt][t], a);
                    acc_gh[t - 2][mt] = a;
                }
            }
    }

    // ---- Wih fragment prefetch (w1f dead; latency hides under sT/P2) ----
    s16x8 wihf[8][3];
    #pragma unroll
    for (int kt = 0; kt < 8; ++kt)
        #pragma unroll
        for (int t = 0; t < 3; ++t)
            wihf[kt][t] = *(const s16x8*)(Wih + ((wv + 8 * t) * 16 + l16) * 256 + kt * 32 + l4 * 8);

    // write h_ioT transposed, + b_in/b_out, split
    #pragma unroll
    for (int t = 0; t < 2; ++t) {
        int n = (wv + 8 * t) * 16 + l16;             // 0..255
        float bias = (n < 128) ? b_in[n] : b_out[n - 128];
        #pragma unroll
        for (int mt = 0; mt < 4; ++mt) {
            int mb = mt * 16 + l4 * 4;
            float x0 = acc_io[t][mt][0] + bias, x1 = acc_io[t][mt][1] + bias;
            float x2 = acc_io[t][mt][2] + bias, x3 = acc_io[t][mt][3] + bias;
            unsigned h01 = pkbf(x0, x1), h23 = pkbf(x2, x3);
            float g0 = __uint_as_float(h01 << 16), g1 = __uint_as_float(h01 & 0xffff0000u);
            float g2 = __uint_as_float(h23 << 16), g3 = __uint_as_float(h23 & 0xffff0000u);
            unsigned l01 = pkbf(x0 - g0, x1 - g1), l23 = pkbf(x2 - g2, x3 - g3);
            u32x2 vh; vh[0] = h01; vh[1] = h23;
            u32x2 vl; vl[0] = l01; vl[1] = l23;
            *(u32x2*)(sThi + n * 72 + mb) = vh;
            *(u32x2*)(sTlo + n * 72 + mb) = vl;
        }
    }
    __syncthreads();

    // ---- P2: inputs[64][256] = [A_in @ h_in | A_out @ h_out] ----
    const int p = wv >> 2, q = wv & 3;
    f32x4 acc2[2][4];
    #pragma unroll
    for (int t = 0; t < 2; ++t)
        #pragma unroll
        for (int m = 0; m < 4; ++m) acc2[t][m] = vzero;

    {
        s16x8 a2[2][4], th2[2][2], tl2[2][2];
        #pragma unroll
        for (int kt = 0; kt < 2; ++kt) {
            #pragma unroll
            for (int mt = 0; mt < 4; ++mt)
                a2[kt][mt] = *(const s16x8*)(sAhi + (mt * 16 + l16) * 136 + p * 64 + kt * 32 + l4 * 8);
            #pragma unroll
            for (int t = 0; t < 2; ++t) {
                int hr = p * 128 + (q + 4 * t) * 16 + l16;
                th2[kt][t] = *(const s16x8*)(sThi + hr * 72 + kt * 32 + l4 * 8);
                tl2[kt][t] = *(const s16x8*)(sTlo + hr * 72 + kt * 32 + l4 * 8);
            }
        }
        #pragma unroll
        for (int kt = 0; kt < 2; ++kt)
            #pragma unroll
            for (int t = 0; t < 2; ++t)
                #pragma unroll
                for (int mt = 0; mt < 4; ++mt) {
                    f32x4 a = acc2[t][mt];
                    a = MFMA(a2[kt][mt], th2[kt][t], a);   // A_hi * h_hi
                    a = MFMA(a2[kt][mt], tl2[kt][t], a);   // A_hi * h_lo
                    acc2[t][mt] = a;
                }
    }
    __syncthreads();   // all waves done READING sT -> overlay may be overwritten
    #pragma unroll
    for (int t = 0; t < 2; ++t) {
        int n = p * 128 + (q + 4 * t) * 16 + l16;    // 0..255
        float bias = (n < 128) ? b_iah[n] : b_ioh[n - 128];
        #pragma unroll
        for (int mt = 0; mt < 4; ++mt) {
            int mb = mt * 16 + l4 * 4;
            #pragma unroll
            for (int rr = 0; rr < 4; rr += 2) {
                float x0 = acc2[t][mt][rr] + bias, x1 = acc2[t][mt][rr + 1] + bias;
                unsigned h = pkbf(x0, x1);
                float g0 = __uint_as_float(h << 16), g1 = __uint_as_float(h & 0xffff0000u);
                unsigned l = pkbf(x0 - g0, x1 - g1);
                sIhi[(mb + rr) * 264 + n]     = (unsigned short)(h & 0xffffu);
                sIhi[(mb + rr + 1) * 264 + n] = (unsigned short)(h >> 16);
                sIlo[(mb + rr) * 264 + n]     = (unsigned short)(l & 0xffffu);
                sIlo[(mb + rr + 1) * 264 + n] = (unsigned short)(l >> 16);
            }
        }
    }
    __syncthreads();

    // ---- P3: gi[64][384] = inputs @ w_ih^T, accumulated into gh accs ----
    f32x4 acc_n[4];
    #pragma unroll
    for (int m = 0; m < 4; ++m) acc_n[m] = vzero;

    #pragma unroll
    for (int mt = 0; mt < 4; ++mt) {
        int off = (mt * 16 + l16) * 264 + l4 * 8;
        ah[0][mt] = *(const s16x8*)(sIhi + off);
        al[0][mt] = *(const s16x8*)(sIlo + off);
    }
    #pragma unroll
    for (int kt = 0; kt < 8; ++kt) {
        const int cur = kt & 1, nxt = cur ^ 1;
        if (kt < 7) {
            #pragma unroll
            for (int mt = 0; mt < 4; ++mt) {
                int off = (mt * 16 + l16) * 264 + (kt + 1) * 32 + l4 * 8;
                ah[nxt][mt] = *(const s16x8*)(sIhi + off);
                al[nxt][mt] = *(const s16x8*)(sIlo + off);
            }
        }
        #pragma unroll
        for (int t = 0; t < 3; ++t)
            #pragma unroll
            for (int mt = 0; mt < 4; ++mt) {
                if (t < 2) {
                    f32x4 a = acc_gh[t][mt];
                    a = MFMA(ah[cur][mt], wihf[kt][t], a);
                    a = MFMA(al[cur][mt], wihf[kt][t], a);
                    acc_gh[t][mt] = a;
                } else {
                    f32x4 a = acc_n[mt];
                    a = MFMA(ah[cur][mt], wihf[kt][t], a);
                    a = MFMA(al[cur][mt], wihf[kt][t], a);
                    acc_n[mt] = a;
                }
            }
    }

    // ---- gates + store; wave wv handles e in [16*wv, 16*wv+16) ----
    {
        const int e = wv * 16 + l16;
        const float br   = b_ih[e]       + b_hh[e];
        const float bi   = b_ih[128 + e] + b_hh[128 + e];
        const float bn_i = b_ih[256 + e];
        const float bn_h = b_hh[256 + e];
        float* Ob = out + (size_t)b * 6400;
        #pragma unroll
        for (int mt = 0; mt < 4; ++mt) {
            #pragma unroll
            for (int r = 0; r < 4; ++r) {
                int m = mt * 16 + l4 * 4 + r;
                if (m < 50) {
                    float argr = acc_gh[0][mt][r] + br;
                    float argi = acc_gh[1][mt][r] + bi;
                    float i_n  = acc_n[mt][r] + bn_i;
                    float h_n  = acc_gh[2][mt][r] + bn_h;
                    float rg = 1.f / (1.f + __expf(-argr));
                    float ig = 1.f / (1.f + __expf(-argi));
                    float ta = i_n + rg * h_n;
                    ta = fminf(fmaxf(ta, -30.f), 30.f);
                    float ex = __expf(2.f * ta);
                    float ng = (ex - 1.f) / (ex + 1.f);
                    float h0 = bf2f(sHhi[m * 136 + e]) + bf2f(sHlo[m * 136 + e]);
                    Ob[m * 128 + e] = h0 + ig * (ng - h0);
                }
            }
        }
    }
}

extern "C" void kernel_launch(void* const* d_in, const int* in_sizes, int n_in,
                              void* d_out, int out_size, void* d_ws, size_t ws_size,
                              hipStream_t stream) {
    const float* A     = (const float*)d_in[0];
    const float* hidden= (const float*)d_in[1];
    const float* w_ih  = (const float*)d_in[2];
    const float* w_hh  = (const float*)d_in[3];
    const float* b_ih  = (const float*)d_in[4];
    const float* b_hh  = (const float*)d_in[5];
    const float* b_iah = (const float*)d_in[6];
    const float* b_ioh = (const float*)d_in[7];
    const float* w_in  = (const float*)d_in[8];
    const float* b_in  = (const float*)d_in[9];
    const float* w_out = (const float*)d_in[10];
    const float* b_out = (const float*)d_in[11];
    float* out = (float*)d_out;

    unsigned short* W1  = (unsigned short*)d_ws;      // 81920 bf16
    unsigned short* Wih = W1 + 81920;                 // 98304 bf16

    wconv_kernel<<<704, 256, 0, stream>>>(w_in, w_out, w_hh, w_ih, W1, Wih);

    const int nbatch = in_sizes[1] / 6400;            // 4096
    (void)hipFuncSetAttribute((const void*)gnn_kernel,
                              hipFuncAttributeMaxDynamicSharedMemorySize, LDS_BYTES);
    gnn_kernel<<<nbatch, 512, LDS_BYTES, stream>>>(A, hidden, W1, Wih,
                                                   b_ih, b_hh, b_iah, b_ioh,
                                                   b_in, b_out, out);
}